// Round 1
// 582.375 us; speedup vs baseline: 1.0031x; 1.0031x over previous
//
#include <hip/hip_runtime.h>
#include <cstdint>
#include <cstddef>

#define T_LEN 2048
#define PAST_MAX 2048
#define HID 4096
#define NHEAD 32
#define DHEAD 128

typedef __bf16 bf16_t;
typedef __bf16 bf16x4 __attribute__((ext_vector_type(4)));
typedef __bf16 bf16x8 __attribute__((ext_vector_type(8)));
typedef float  f32x4  __attribute__((ext_vector_type(4)));
typedef float  f32x16 __attribute__((ext_vector_type(16)));
typedef unsigned int u32x4 __attribute__((ext_vector_type(4)));

__device__ __forceinline__ void gload16(const void* g, void* l){
  __builtin_amdgcn_global_load_lds((const __attribute__((address_space(1))) void*)g,
                                   (__attribute__((address_space(3))) void*)l,
                                   16, 0, 0);
}

__device__ __forceinline__ unsigned pack_bf16(float a, float b){
  const unsigned ua = __builtin_bit_cast(unsigned short, (bf16_t)a);
  const unsigned ub = __builtin_bit_cast(unsigned short, (bf16_t)b);
  return ua | (ub << 16);
}

// ---------------- fused f32 -> bf16 for X and past_k ----------------
__global__ void cvt2_k(const float* __restrict__ a, bf16_t* __restrict__ ao,
                       const float* __restrict__ b, bf16_t* __restrict__ bo, int n4){
  int i = blockIdx.x * 256 + threadIdx.x;
  if (i < n4){
    const float4 v = ((const float4*)a)[i];
    bf16x4 o = { (bf16_t)v.x, (bf16_t)v.y, (bf16_t)v.z, (bf16_t)v.w };
    ((bf16x4*)ao)[i] = o;
  } else {
    i -= n4;
    const float4 v = ((const float4*)b)[i];
    bf16x4 o = { (bf16_t)v.x, (bf16_t)v.y, (bf16_t)v.z, (bf16_t)v.w };
    ((bf16x4*)bo)[i] = o;
  }
}

// ---------------- f32 [B][R][C] -> bf16 [B][C][R], 64x64 tiles ----------------
__global__ __launch_bounds__(256) void transpose2_k(const float* __restrict__ in,
                                                    bf16_t* __restrict__ out, int R, int C){
  __shared__ float tile[64][65];
  const int r0 = blockIdx.x << 6, c0 = blockIdx.y << 6;
  const size_t bo = (size_t)blockIdx.z * (size_t)R * (size_t)C;
  const int tx = threadIdx.x & 15, ty = threadIdx.x >> 4;
#pragma unroll
  for (int k = 0; k < 4; ++k){
    const float4 v = *(const float4*)(in + bo + (size_t)(r0 + ty + 16*k) * C + c0 + tx*4);
    float* tp = &tile[ty + 16*k][tx*4];
    tp[0] = v.x; tp[1] = v.y; tp[2] = v.z; tp[3] = v.w;
  }
  __syncthreads();
  const int rr0 = (threadIdx.x & 7) * 8;
  const int ccb = threadIdx.x >> 3;     // 0..31
#pragma unroll
  for (int k = 0; k < 2; ++k){
    const int cc = ccb + 32*k;
    bf16x8 o;
#pragma unroll
    for (int j = 0; j < 8; ++j) o[j] = (bf16_t)tile[rr0 + j][cc];
    *(bf16x8*)(out + bo + (size_t)(c0 + cc) * R + r0 + rr0) = o;
  }
}

// ---------------- fused transpose of Wq/Wk/Wv (z selects) ----------------
__global__ __launch_bounds__(256) void transpose3_k(
    const float* __restrict__ s0, const float* __restrict__ s1, const float* __restrict__ s2,
    bf16_t* __restrict__ d0, bf16_t* __restrict__ d1, bf16_t* __restrict__ d2){
  __shared__ float tile[64][65];
  const float* in = (blockIdx.z == 0) ? s0 : (blockIdx.z == 1) ? s1 : s2;
  bf16_t* out = (blockIdx.z == 0) ? d0 : (blockIdx.z == 1) ? d1 : d2;
  const int r0 = blockIdx.x << 6, c0 = blockIdx.y << 6;
  const int tx = threadIdx.x & 15, ty = threadIdx.x >> 4;
#pragma unroll
  for (int k = 0; k < 4; ++k){
    const float4 v = *(const float4*)(in + (size_t)(r0 + ty + 16*k) * HID + c0 + tx*4);
    float* tp = &tile[ty + 16*k][tx*4];
    tp[0] = v.x; tp[1] = v.y; tp[2] = v.z; tp[3] = v.w;
  }
  __syncthreads();
  const int rr0 = (threadIdx.x & 7) * 8;
  const int ccb = threadIdx.x >> 3;
#pragma unroll
  for (int k = 0; k < 2; ++k){
    const int cc = ccb + 32*k;
    bf16x8 o;
#pragma unroll
    for (int j = 0; j < 8; ++j) o[j] = (bf16_t)tile[rr0 + j][cc];
    *(bf16x8*)(out + (size_t)(c0 + cc) * HID + r0 + rr0) = o;
  }
}

// ---------------- RoPE in place on K only (Q roped in-register inside attn) ------------
__global__ void ropek_k(bf16_t* __restrict__ K, const int* __restrict__ pos){
  const int idx = blockIdx.x * 256 + threadIdx.x;     // 32*2048*64 total
  const int i = idx & 63;
  const int t = (idx >> 6) & (T_LEN - 1);
  const int h = idx >> 17;
  const size_t base = ((size_t)h * T_LEN + t) * DHEAD;
  const float p = (float)pos[t];
  const float inv = __expf(-(float)i * 0.14391156605212898f);  // ln(10000)/64
  const float ang = p * inv;
  float sn, cs;
  sincosf(ang, &sn, &cs);
  const float b0 = (float)K[base + i], b1 = (float)K[base + i + 64];
  K[base + i]      = (bf16_t)(b0 * cs - b1 * sn);
  K[base + i + 64] = (bf16_t)(b1 * cs + b0 * sn);
}

// ------------- QKV: 256x128 4-phase interleaved GEMM (gemm4p schedule, 4Mx2N) ----------
// Port of the R15-proven out-proj 4-phase schedule to the QKV GEMM: BK=64, 96 KB LDS,
// counted vmcnt(2) (never drains to 0 in main loop), setprio around each 16-MFMA cluster.
// Grid 768 = 8 mt x 96 (z,nt), 1 block/CU -> exactly 3 full waves, no tail.
// Epilogue keeps gemm2b's 3-way output-layout select (Q/K [H][T][D], V^T [H][D][T]).
__global__ __launch_bounds__(512, 1) void gemmqkv4p_k(
    const bf16_t* __restrict__ A,
    const bf16_t* __restrict__ B0, const bf16_t* __restrict__ B1, const bf16_t* __restrict__ B2,
    bf16_t* __restrict__ OQ, bf16_t* __restrict__ OK2, bf16_t* __restrict__ OVT, int cpx)
{
  const int bid = blockIdx.x;
  const int wg  = (bid & 7) * cpx + (bid >> 3);   // cpx = 96, 768 % 8 == 0 -> bijective
  const int mt  = wg & 7;
  const int rest = wg >> 3;          // 0..95
  const int z   = rest >> 5;         // 0..2 selects Wq/Wk/Wv
  const int nt  = rest & 31;         // 0..31
  const int m0  = mt << 8;
  const int n0  = nt << 7;
  const bf16_t* __restrict__ B = (z == 0) ? B0 : (z == 1) ? B1 : B2;

  const int tid = threadIdx.x;
  const int wv = tid >> 6, lane = tid & 63, lm = lane & 15, g = lane >> 4;
  const int wr = wv >> 1, wc = wv & 1;      // 4 M-groups x 2 N-groups

  __shared__ __align__(16) char smem[98304];

  const f32x4 fzero = {0.f, 0.f, 0.f, 0.f};
  f32x4 acc[4][4];
#pragma unroll
  for (int i = 0; i < 4; ++i)
#pragma unroll
    for (int j = 0; j < 4; ++j) acc[i][j] = fzero;

  // staging: op = 16 KB = 1024 chunks (128 rows x 8); 2 loads/thread
  int srow[2], schk[2];
#pragma unroll
  for (int i = 0; i < 2; ++i){
    const int c = i * 512 + tid;
    srow[i] = c >> 3;
    schk[i] = (c & 7) ^ (srow[i] & 7);
  }
  const int sdst0 = ((0 * 512 + wv * 64) << 4);
  const int sdst1 = ((1 * 512 + wv * 64) << 4);

  // ops: 0 = A rows 0-127, 1 = A rows 128-255, 2 = B rows 0-127
  auto stg = [&](int kt, int op){
    if (kt < 64){
      char* dst = smem + (kt & 1) * 49152 + op * 16384;
      const bf16_t* base = (op < 2) ? A + (size_t)(m0 + (op << 7)) * HID
                                    : B + (size_t)n0 * HID;
      base += kt * 64;
      gload16(base + (size_t)srow[0] * HID + schk[0] * 8, dst + sdst0);
      gload16(base + (size_t)srow[1] * HID + schk[1] * 8, dst + sdst1);
    }
  };

  // fragment read constants (all frag rows == lm mod 8 -> same swizzle)
  const int koff0 = ((g)     ^ (lm & 7)) << 4;
  const int koff1 = ((4 + g) ^ (lm & 7)) << 4;
  const int abase = ((wr >> 1) << 14) + ((((wr & 1) << 6) + lm) << 7);
  const int bbase = 32768 + ((((wc << 6)) + lm) << 7);

  bf16x8 bfr[4][2];
  auto dsB = [&](int buf){
    const char* p = smem + buf * 49152 + bbase;
#pragma unroll
    for (int ni = 0; ni < 4; ++ni){
      bfr[ni][0] = *(const bf16x8*)(p + ni * 2048 + koff0);
      bfr[ni][1] = *(const bf16x8*)(p + ni * 2048 + koff1);
    }
  };

  // prologue: B(0), A(0), B(1); force B(0)+A(0), keep B(1) in flight
  stg(0, 2);
  stg(0, 0); stg(0, 1);
  stg(1, 2);
  asm volatile("s_waitcnt vmcnt(2)" ::: "memory");
  __builtin_amdgcn_s_barrier();

  for (int t = 0; t < 32; ++t){
    const int c0 = 2 * t, c1 = 2 * t + 1;
    const bool last = (t == 31);

#pragma unroll
    for (int half = 0; half < 2; ++half){
      const char* bufp = smem + half * 49152;
      bf16x8 afr[2][2];
      dsB(half);
#pragma unroll
      for (int mf = 0; mf < 2; ++mf){
        afr[mf][0] = *(const bf16x8*)(bufp + abase + mf * 2048 + koff0);
        afr[mf][1] = *(const bf16x8*)(bufp + abase + mf * 2048 + koff1);
      }
      if (half == 0){ stg(c1, 0); stg(c1, 1); }
      else          { stg(c0 + 2, 0); stg(c0 + 2, 1); }
      __builtin_amdgcn_s_barrier();
      asm volatile("s_waitcnt lgkmcnt(0)" ::: "memory");
      __builtin_amdgcn_s_setprio(1);
#pragma unroll
      for (int kk = 0; kk < 2; ++kk)
#pragma unroll
        for (int mf = 0; mf < 2; ++mf)
#pragma unroll
          for (int ni = 0; ni < 4; ++ni)
            acc[mf][ni] = __builtin_amdgcn_mfma_f32_16x16x32_bf16(afr[mf][kk], bfr[ni][kk], acc[mf][ni], 0, 0, 0);
      __builtin_amdgcn_s_setprio(0);
      __builtin_amdgcn_s_barrier();

#pragma unroll
      for (int mf = 0; mf < 2; ++mf){
        afr[mf][0] = *(const bf16x8*)(bufp + abase + (mf + 2) * 2048 + koff0);
        afr[mf][1] = *(const bf16x8*)(bufp + abase + (mf + 2) * 2048 + koff1);
      }
      if (half == 0) stg(c0 + 2, 2);
      else           stg(c1 + 2, 2);
      if (last) asm volatile("s_waitcnt vmcnt(0)" ::: "memory");
      else      asm volatile("s_waitcnt vmcnt(2)" ::: "memory");
      __builtin_amdgcn_s_barrier();
      asm volatile("s_waitcnt lgkmcnt(0)" ::: "memory");
      __builtin_amdgcn_s_setprio(1);
#pragma unroll
      for (int kk = 0; kk < 2; ++kk)
#pragma unroll
        for (int mf = 0; mf < 2; ++mf)
#pragma unroll
          for (int ni = 0; ni < 4; ++ni)
            acc[mf + 2][ni] = __builtin_amdgcn_mfma_f32_16x16x32_bf16(afr[mf][kk], bfr[ni][kk], acc[mf + 2][ni], 0, 0, 0);
      __builtin_amdgcn_s_setprio(0);
      __builtin_amdgcn_s_barrier();
    }
  }

  // epilogue: 3-way layout select (Q/K [H][T][D], V^T [H][D][T])
#pragma unroll
  for (int ni = 0; ni < 4; ++ni){
    const int col = n0 + wc * 64 + ni * 16 + lm;
    const int hh = col >> 7, dd = col & 127;
#pragma unroll
    for (int mf = 0; mf < 4; ++mf)
#pragma unroll
      for (int r = 0; r < 4; ++r){
        const int trow = m0 + wr * 64 + mf * 16 + g * 4 + r;
        const bf16_t v = (bf16_t)acc[mf][ni][r];
        if (z == 2)      OVT[((size_t)hh * DHEAD + dd) * T_LEN + trow] = v;
        else if (z == 1) OK2[((size_t)hh * T_LEN + trow) * DHEAD + dd] = v;
        else             OQ [((size_t)hh * T_LEN + trow) * DHEAD + dd] = v;
      }
  }
}

// ------------- out-proj: 256x128 4-phase interleaved GEMM (R15-proven, 4Mx2N) ----------
__global__ __launch_bounds__(512, 1) void gemm4p_k(
    const bf16_t* __restrict__ A, const bf16_t* __restrict__ B,
    float* __restrict__ OF, int cpx)
{
  const int bid = blockIdx.x;
  const int wg  = (bid & 7) * cpx + (bid >> 3);
  const int mt  = wg & 7;
  const int nt  = wg >> 3;
  const int m0  = mt << 8;
  const int n0  = nt << 7;

  const int tid = threadIdx.x;
  const int wv = tid >> 6, lane = tid & 63, lm = lane & 15, g = lane >> 4;
  const int wr = wv >> 1, wc = wv & 1;      // 4 M-groups x 2 N-groups

  __shared__ __align__(16) char smem[98304];

  const f32x4 fzero = {0.f, 0.f, 0.f, 0.f};
  f32x4 acc[4][4];
#pragma unroll
  for (int i = 0; i < 4; ++i)
#pragma unroll
    for (int j = 0; j < 4; ++j) acc[i][j] = fzero;

  // staging: op = 16 KB = 1024 chunks (128 rows x 8); 2 loads/thread
  int srow[2], schk[2];
#pragma unroll
  for (int i = 0; i < 2; ++i){
    const int c = i * 512 + tid;
    srow[i] = c >> 3;
    schk[i] = (c & 7) ^ (srow[i] & 7);
  }
  const int sdst0 = ((0 * 512 + wv * 64) << 4);
  const int sdst1 = ((1 * 512 + wv * 64) << 4);

  // ops: 0 = A rows 0-127, 1 = A rows 128-255, 2 = B rows 0-127
  auto stg = [&](int kt, int op){
    if (kt < 64){
      char* dst = smem + (kt & 1) * 49152 + op * 16384;
      const bf16_t* base = (op < 2) ? A + (size_t)(m0 + (op << 7)) * HID
                                    : B + (size_t)n0 * HID;
      base += kt * 64;
      gload16(base + (size_t)srow[0] * HID + schk[0] * 8, dst + sdst0);
      gload16(base + (size_t)srow[1] * HID + schk[1] * 8, dst + sdst1);
    }
  };

  // fragment read constants (all frag rows == lm mod 8 -> same swizzle)
  const int koff0 = ((g)     ^ (lm & 7)) << 4;
  const int koff1 = ((4 + g) ^ (lm & 7)) << 4;
  const int abase = ((wr >> 1) << 14) + ((((wr & 1) << 6) + lm) << 7);
  const int bbase = 32768 + ((((wc << 6)) + lm) << 7);

  bf16x8 bfr[4][2];
  auto dsB = [&](int buf){
    const char* p = smem + buf * 49152 + bbase;
#pragma unroll
    for (int ni = 0; ni < 4; ++ni){
      bfr[ni][0] = *(const bf16x8*)(p + ni * 2048 + koff0);
      bfr[ni][1] = *(const bf16x8*)(p + ni * 2048 + koff1);
    }
  };

  // prologue: B(0), A(0), B(1); force B(0)+A(0), keep B(1) in flight
  stg(0, 2);
  stg(0, 0); stg(0, 1);
  stg(1, 2);
  asm volatile("s_waitcnt vmcnt(2)" ::: "memory");
  __builtin_amdgcn_s_barrier();

  for (int t = 0; t < 32; ++t){
    const int c0 = 2 * t, c1 = 2 * t + 1;
    const bool last = (t == 31);

#pragma unroll
    for (int half = 0; half < 2; ++half){
      const char* bufp = smem + half * 49152;
      bf16x8 afr[2][2];
      dsB(half);
#pragma unroll
      for (int mf = 0; mf < 2; ++mf){
        afr[mf][0] = *(const bf16x8*)(bufp + abase + mf * 2048 + koff0);
        afr[mf][1] = *(const bf16x8*)(bufp + abase + mf * 2048 + koff1);
      }
      if (half == 0){ stg(c1, 0); stg(c1, 1); }
      else          { stg(c0 + 2, 0); stg(c0 + 2, 1); }
      __builtin_amdgcn_s_barrier();
      asm volatile("s_waitcnt lgkmcnt(0)" ::: "memory");
      __builtin_amdgcn_s_setprio(1);
#pragma unroll
      for (int kk = 0; kk < 2; ++kk)
#pragma unroll
        for (int mf = 0; mf < 2; ++mf)
#pragma unroll
          for (int ni = 0; ni < 4; ++ni)
            acc[mf][ni] = __builtin_amdgcn_mfma_f32_16x16x32_bf16(afr[mf][kk], bfr[ni][kk], acc[mf][ni], 0, 0, 0);
      __builtin_amdgcn_s_setprio(0);
      __builtin_amdgcn_s_barrier();

#pragma unroll
      for (int mf = 0; mf < 2; ++mf){
        afr[mf][0] = *(const bf16x8*)(bufp + abase + (mf + 2) * 2048 + koff0);
        afr[mf][1] = *(const bf16x8*)(bufp + abase + (mf + 2) * 2048 + koff1);
      }
      if (half == 0) stg(c0 + 2, 2);
      else           stg(c1 + 2, 2);
      if (last) asm volatile("s_waitcnt vmcnt(0)" ::: "memory");
      else      asm volatile("s_waitcnt vmcnt(2)" ::: "memory");
      __builtin_amdgcn_s_barrier();
      asm volatile("s_waitcnt lgkmcnt(0)" ::: "memory");
      __builtin_amdgcn_s_setprio(1);
#pragma unroll
      for (int kk = 0; kk < 2; ++kk)
#pragma unroll
        for (int mf = 0; mf < 2; ++mf)
#pragma unroll
          for (int ni = 0; ni < 4; ++ni)
            acc[mf + 2][ni] = __builtin_amdgcn_mfma_f32_16x16x32_bf16(afr[mf][kk], bfr[ni][kk], acc[mf + 2][ni], 0, 0, 0);
      __builtin_amdgcn_s_setprio(0);
      __builtin_amdgcn_s_barrier();
    }
  }

  // epilogue
#pragma unroll
  for (int ni = 0; ni < 4; ++ni){
    const int col = n0 + wc * 64 + ni * 16 + lm;
#pragma unroll
    for (int mf = 0; mf < 4; ++mf)
#pragma unroll
      for (int r = 0; r < 4; ++r){
        const int trow = m0 + wr * 64 + mf * 16 + g * 4 + r;
        OF[(size_t)trow * HID + col] = acc[mf][ni][r];
      }
  }
}

// ---------------- flash attention: 32x32 MFMA, counted-vmcnt KV pipeline ----------------
// Q roped+scaled in-register (per-lane pair d <-> d+64 lives in qf[dc] / qf[dc+4]).
__global__ __launch_bounds__(256, 2) void attn2_k(
    const bf16_t* __restrict__ Q,
    const bf16_t* __restrict__ Kc,
    const bf16_t* __restrict__ VTc,
    const bf16_t* __restrict__ Kp,
    const bf16_t* __restrict__ VTp,
    bf16_t* __restrict__ Ctx,
    const int* __restrict__ plen_p,
    const int* __restrict__ pos)
{
  // XCD-chunked + complementary-qb balance remap (bijective)
  const int bid = blockIdx.x;          // 0..511
  const int xcd = bid & 7;
  const int k   = bid >> 3;            // 0..63
  const int ho  = k >> 4;              // 0..3
  const int qraw= k & 15;
  const int h   = (xcd << 2) | ho;
  const int qb  = (ho & 2) ? (15 - qraw) : qraw;

  const int tid = threadIdx.x;
  const int w = tid >> 6, lane = tid & 63, l31 = lane & 31, hi = lane >> 5;
  const int qw0 = qb * 128 + w * 32;
  const int qrow = qw0 + l31;
  const int plen = plen_p[0];
  const int npast = (plen + 63) >> 6;
  const int NT = npast + 2 * qb + 2;

  __shared__ __align__(16) char smem[65536 + 512];
  float* lred = (float*)(smem + 65536);   // per-wave 32-float broadcast slice

  // Q fragments from global; rope+scale in-register (consumes loads before stage(0))
  const bf16_t* qbase = Q + ((size_t)h * T_LEN + qrow) * DHEAD;
  bf16x8 qf[8];
#pragma unroll
  for (int dc = 0; dc < 8; ++dc)
    qf[dc] = *(const bf16x8*)(qbase + dc * 16 + 8 * hi);
  {
    const float ppos = (float)pos[qrow];
    const float qs = 0.08838834764831845f;   // 1/sqrt(128)
#pragma unroll
    for (int dc = 0; dc < 4; ++dc)
#pragma unroll
      for (int j = 0; j < 8; ++j){
        const int fi = dc * 16 + 8 * hi + j;               // freq index = d (< 64)
        const float invf = __expf(-(float)fi * 0.14391156605212898f);
        float sn, cs;
        sincosf(ppos * invf, &sn, &cs);
        const float a0 = (float)qf[dc][j], a1 = (float)qf[dc + 4][j];
        qf[dc][j]     = (bf16_t)((a0 * cs - a1 * sn) * qs);
        qf[dc + 4][j] = (bf16_t)((a1 * cs + a0 * sn) * qs);
      }
  }
  __builtin_amdgcn_sched_barrier(0);

  const f32x16 fz = {0.f,0.f,0.f,0.f,0.f,0.f,0.f,0.f,0.f,0.f,0.f,0.f,0.f,0.f,0.f,0.f};
  f32x16 o[4] = {fz, fz, fz, fz};
  float m = -1e30f, l = 0.f;

  auto stage = [&](int t, int buf){
    const bf16_t* kb; const bf16_t* vb;
    if (t < npast){
      const int s0 = t * 64;
      kb = Kp  + ((size_t)h * PAST_MAX + s0) * DHEAD;
      vb = VTp + (size_t)h * DHEAD * PAST_MAX + s0;
    } else {
      const int s0 = (t - npast) * 64;
      kb = Kc  + ((size_t)h * T_LEN + s0) * DHEAD;
      vb = VTc + (size_t)h * DHEAD * T_LEN + s0;
    }
    char* kl = smem + buf * 32768;
    char* vl = kl + 16384;
#pragma unroll
    for (int i = 0; i < 4; ++i){
      const int c = i * 256 + w * 64 + lane;
      const int krow = c >> 4, kcol = c & 15;          // K [64][128] bf16, 16 chunks/row
      gload16(kb + (size_t)krow * DHEAD + ((kcol ^ (krow & 7)) << 3), kl + (i * 256 + w * 64) * 16);
      const int vrow = c >> 3, vcol = c & 7;           // V^T [128][64] bf16, 8 chunks/row
      gload16(vb + (size_t)vrow * 2048 + ((vcol ^ (vrow & 7)) << 3), vl + (i * 256 + w * 64) * 16);
    }
  };

  stage(0, 0);
  __builtin_amdgcn_sched_barrier(0);

  for (int t = 0; t < NT; ++t){
    const int cur = t & 1;
    if (t + 1 < NT){
      stage(t + 1, cur ^ 1);
      asm volatile("s_waitcnt vmcnt(8)" ::: "memory");   // tile t landed; t+1 in flight
    } else {
      asm volatile("s_waitcnt vmcnt(0)" ::: "memory");
    }
    __builtin_amdgcn_sched_barrier(0);
    __builtin_amdgcn_s_barrier();
    __builtin_amdgcn_sched_barrier(0);

    const bool isc = (t >= npast);
    const int s0c = (t - npast) * 64;
    const bool active = !isc || (s0c <= qw0 + 31);

    if (active){
      char* kl = smem + cur * 32768;
      char* vl = kl + 16384;

      f32x16 sacc[2] = {fz, fz};
      __builtin_amdgcn_s_setprio(1);
#pragma unroll
      for (int kvh = 0; kvh < 2; ++kvh){
        const int krow = (kvh << 5) + l31;
        const int kbo = krow << 8;
        const int sw = (krow & 7) << 4;
#pragma unroll
        for (int dc = 0; dc < 8; ++dc){
          const bf16x8 kf = *(const bf16x8*)(kl + kbo + ((dc * 32 + 16 * hi) ^ sw));
          sacc[kvh] = __builtin_amdgcn_mfma_f32_32x32x16_bf16(kf, qf[dc], sacc[kvh], 0, 0, 0);
        }
      }
      __builtin_amdgcn_s_setprio(0);

      // mask-hoist: only diagonal/boundary tiles pay the per-element mask chain
      const bool mcur  = isc && (s0c + 63 > qw0);
      const bool mpast = !isc && ((t + 1) * 64 > plen);
      float pv[2][16];
      float pm = -1e30f;
      if (mcur | mpast){
#pragma unroll
        for (int kvh = 0; kvh < 2; ++kvh)
#pragma unroll
          for (int r = 0; r < 16; ++r){
            float x = sacc[kvh][r];
            const int kvoff = (kvh << 5) + (r & 3) + 8 * (r >> 2) + 4 * hi;
            if (mcur  && (s0c + kvoff >  qrow)) x = -1e30f;
            if (mpast && (t * 64 + kvoff >= plen)) x = -1e30f;
            pv[kvh][r] = x;
            pm = fmaxf(pm, x);
          }
      } else {
#pragma unroll
        for (int kvh = 0; kvh < 2; ++kvh)
#pragma unroll
          for (int r = 0; r < 16; ++r){
            pv[kvh][r] = sacc[kvh][r];
            pm = fmaxf(pm, sacc[kvh][r]);
          }
      }
      pm = fmaxf(pm, __shfl_xor(pm, 32));

      // defer-max: rescale only when max grows past threshold
      if (!__all(pm - m <= 8.f)){
        const float mn = fmaxf(m, pm);
        const float corr = __expf(m - mn);
        m = mn;
        l *= corr;
        if (hi == 0) lred[(w << 5) + l31] = corr;
        asm volatile("s_waitcnt lgkmcnt(0)" ::: "memory");
#pragma unroll
        for (int r = 0; r < 16; ++r){
          const float cc = lred[(w << 5) + (r & 3) + 8 * (r >> 2) + 4 * hi];
#pragma unroll
          for (int nb = 0; nb < 4; ++nb) o[nb][r] *= cc;
        }
      }

      float sum = 0.f;
#pragma unroll
      for (int kvh = 0; kvh < 2; ++kvh)
#pragma unroll
        for (int r = 0; r < 16; ++r){
          const float pe = __expf(pv[kvh][r] - m);
          pv[kvh][r] = pe;
          sum += pe;
        }
      sum += __shfl_xor(sum, 32);
      l += sum;

      // pack own 32 P to 16 words; partner-exchange 8 words -> PV A-frags
      unsigned wds[2][8];
#pragma unroll
      for (int kvh = 0; kvh < 2; ++kvh)
#pragma unroll
        for (int i = 0; i < 8; ++i)
          wds[kvh][i] = pack_bf16(pv[kvh][2 * i], pv[kvh][2 * i + 1]);

      bf16x8 pf[4];
#pragma unroll
      for (int ks = 0; ks < 4; ++ks){
        const int s = ks & 1, kvh = ks >> 1;
        const unsigned a0 = hi ? wds[kvh][4 * s]     : wds[kvh][4 * s + 2];
        const unsigned a1 = hi ? wds[kvh][4 * s + 1] : wds[kvh][4 * s + 3];
        const unsigned z0 = (unsigned)__shfl_xor((int)a0, 32);
        const unsigned z1 = (unsigned)__shfl_xor((int)a1, 32);
        u32x4 fw;
        fw[0] = hi ? z0 : wds[kvh][4 * s];
        fw[1] = hi ? z1 : wds[kvh][4 * s + 1];
        fw[2] = hi ? wds[kvh][4 * s + 2] : z0;
        fw[3] = hi ? wds[kvh][4 * s + 3] : z1;
        pf[ks] = __builtin_bit_cast(bf16x8, fw);
      }

      // PV: O[q][dv] += P·V, V^T frags from LDS
      __builtin_amdgcn_s_setprio(1);
#pragma unroll
      for (int ks = 0; ks < 4; ++ks)
#pragma unroll
        for (int nb = 0; nb < 4; ++nb){
          const int vrow = (nb << 5) + l31;
          const bf16x8 vf = *(const bf16x8*)(vl + (vrow << 7) + ((ks * 32 + 16 * hi) ^ ((vrow & 7) << 4)));
          o[nb] = __builtin_amdgcn_mfma_f32_32x32x16_bf16(pf[ks], vf, o[nb], 0, 0, 0);
        }
      __builtin_amdgcn_s_setprio(0);
    }
    __builtin_amdgcn_sched_barrier(0);
    __builtin_amdgcn_s_barrier();       // WAR release: buf cur free for t+2's stage
  }

  // epilogue: O / l -> Ctx [T][HID]
  if (hi == 0) lred[(w << 5) + l31] = l;
  asm volatile("s_waitcnt lgkmcnt(0)" ::: "memory");
#pragma unroll
  for (int r = 0; r < 16; ++r){
    const int cr = (r & 3) + 8 * (r >> 2) + 4 * hi;
    const float li = 1.f / lred[(w << 5) + cr];
    const int trow = qw0 + cr;
    bf16_t* cb = Ctx + (size_t)trow * HID + h * DHEAD + l31;
#pragma unroll
    for (int nb = 0; nb < 4; ++nb)
      cb[nb << 5] = (bf16_t)(o[nb][r] * li);
  }
}

// ---------------- launcher ----------------
extern "C" void kernel_launch(void* const* d_in, const int* in_sizes, int n_in,
                              void* d_out, int out_size, void* d_ws, size_t ws_size,
                              hipStream_t stream)
{
  const float* X   = (const float*)d_in[0];
  const float* Wq  = (const float*)d_in[2];
  const float* Wk  = (const float*)d_in[3];
  const float* Wv  = (const float*)d_in[4];
  const float* Wo  = (const float*)d_in[5];
  const float* PKi = (const float*)d_in[6];
  const float* PVi = (const float*)d_in[7];
  const int* POS   = (const int*)d_in[8];
  const int* PLEN  = (const int*)d_in[9];
  float* OUT = (float*)d_out;

  char* ws = (char*)d_ws;
  const size_t SZ_XB  = (size_t)T_LEN * HID * 2;             // 16 MiB
  const size_t SZ_W   = (size_t)HID * HID * 2;               // 32 MiB
  const size_t SZ_HTD = (size_t)NHEAD * T_LEN * DHEAD * 2;   // 16 MiB

  bf16_t* XB  = (bf16_t*)(ws);
  bf16_t* WT0 = (bf16_t*)(ws + SZ_XB);
  bf16_t* WT1 = (bf16_t*)(ws + SZ_XB + SZ_W);
  bf16_t* WT2 = (bf16_t*)(ws + SZ_XB + 2 * SZ_W);
  char* p = ws + SZ_XB + 3 * SZ_W;
  bf16_t* QB   = (bf16_t*)p; p += SZ_HTD;
  bf16_t* KB   = (bf16_t*)p; p += SZ_HTD;
  bf16_t* VTB  = (bf16_t*)p; p += SZ_HTD;
  bf16_t* KPB  = (bf16_t*)p; p += SZ_HTD;
  bf16_t* VPTB = (bf16_t*)p; p += SZ_HTD;
  bf16_t* CTX  = (bf16_t*)p; p += SZ_HTD;
  bf16_t* WOT  = QB;   // reuse QB+KB (32 MiB contiguous) after attention

  dim3 blk256(256);
  dim3 blk512(512);
  cvt2_k<<<16384, blk256, 0, stream>>>(X, XB, PKi, KPB, T_LEN * HID / 4);
  transpose3_k<<<dim3(64,64,3), blk256, 0, stream>>>(Wq, Wk, Wv, WT0, WT1, WT2);
  transpose2_k<<<dim3(32,2,32), blk256, 0, stream>>>(PVi, VPTB, PAST_MAX, DHEAD);

  gemmqkv4p_k<<<768, blk512, 0, stream>>>(XB, WT0, WT1, WT2, QB, KB, VTB, 96);
  ropek_k<<<16384, blk256, 0, stream>>>(KB, POS);
  attn2_k<<<512, blk256, 0, stream>>>(QB, KB, VTB, KPB, VPTB, CTX, PLEN, POS);

  transpose2_k<<<dim3(64,64,1), blk256, 0, stream>>>(Wo, WOT, HID, HID);
  gemm4p_k<<<256, blk512, 0, stream>>>(CTX, WOT, OUT, 32);
}